// Round 2
// baseline (969.558 us; speedup 1.0000x reference)
//
#include <hip/hip_runtime.h>
#include <stdint.h>

#define N_NODES 50000
#define N_EDGES 800000
#define IN_F 128
#define HEADS 8
#define HEAD_DIM 16
#define OUT_F 128
#define ALPHA 0.2f
#define EPSV 1e-6f

__device__ __forceinline__ void atomicMaxF(float* addr, float val) {
    int* ia = (int*)addr;
    int old = *ia;
    while (__int_as_float(old) < val) {
        int assumed = old;
        old = atomicCAS(ia, assumed, __float_as_int(val));
        if (old == assumed) break;
    }
}

// ---------------- init: zero out (6.4M f32) + denom (400k f32), maxv = -inf
__global__ __launch_bounds__(256) void k_init(float* __restrict__ outb,
                                              float* __restrict__ denom,
                                              float* __restrict__ maxv) {
    int i = blockIdx.x * 256 + threadIdx.x;
    float4 z = make_float4(0.f, 0.f, 0.f, 0.f);
    if (i < 1600000) ((float4*)outb)[i] = z;
    else if (i < 1700000) ((float4*)denom)[i - 1600000] = z;
    if (i < 8) maxv[i] = -INFINITY;
}

// ---------------- k1: h = x @ W  (+ fused s_src/s_tgt projections)
// one wave per node; lane owns cols c0=lane, c1=lane+64 (col = head*16+d)
__global__ __launch_bounds__(256) void k1_gemm(const float* __restrict__ x,
                                               const float* __restrict__ W,
                                               const float* __restrict__ a,
                                               float* __restrict__ h,
                                               float* __restrict__ s_src,
                                               float* __restrict__ s_tgt) {
    __shared__ float a_s[128];
    __shared__ float a_t[128];
    __shared__ float xrow[4][IN_F];
    int t = threadIdx.x;
    // a: (8,32,1) -> a_src[h][d]=a[h*32+d], a_tgt[h][d]=a[h*32+16+d]
    {
        int hh = t >> 5, j = t & 31;
        float v = a[t];
        if (j < 16) a_s[hh * 16 + j] = v;
        else        a_t[hh * 16 + (j - 16)] = v;
    }
    int wave = t >> 6, lane = t & 63;
    int n = blockIdx.x * 4 + wave;   // 12500*4 == 50000 exactly
    const float2* xg = (const float2*)(x + (size_t)n * IN_F);
    float2 pk = xg[lane];
    xrow[wave][2 * lane]     = pk.x;
    xrow[wave][2 * lane + 1] = pk.y;
    __syncthreads();

    int d = lane & 15, q = lane >> 4;
    int h0 = q, h1 = q + 4;
    int base0 = h0 * 2048 + d;     // W[h][f][d] = h*2048 + f*16 + d
    int base1 = h1 * 2048 + d;
    float acc0 = 0.f, acc1 = 0.f;
#pragma unroll 8
    for (int f = 0; f < IN_F; f++) {
        float xv = xrow[wave][f];
        acc0 = fmaf(xv, W[base0 + f * 16], acc0);
        acc1 = fmaf(xv, W[base1 + f * 16], acc1);
    }
    int c0 = lane;        // h0*16 + d
    int c1 = lane + 64;   // h1*16 + d
    h[(size_t)n * 128 + c0] = acc0;
    h[(size_t)n * 128 + c1] = acc1;

    float ps = acc0 * a_s[c0], pt = acc0 * a_t[c0];
    float qs = acc1 * a_s[c1], qt = acc1 * a_t[c1];
#pragma unroll
    for (int off = 1; off < 16; off <<= 1) {
        ps += __shfl_xor(ps, off, 64);
        pt += __shfl_xor(pt, off, 64);
        qs += __shfl_xor(qs, off, 64);
        qt += __shfl_xor(qt, off, 64);
    }
    if (d == 0) {
        s_src[n * 8 + h0] = ps;  s_tgt[n * 8 + h0] = pt;
        s_src[n * 8 + h1] = qs;  s_tgt[n * 8 + h1] = qt;
    }
}

// ---------------- k2: per-edge leaky scores + global per-head max
__global__ __launch_bounds__(256) void k2_scores(const int* __restrict__ srcA,
                                                 const int* __restrict__ tgtA,
                                                 const float* __restrict__ s_src,
                                                 const float* __restrict__ s_tgt,
                                                 float* __restrict__ scores,
                                                 float* __restrict__ maxv) {
    __shared__ float red[4][8];
    int t = threadIdx.x;
    int e = blockIdx.x * 256 + t;    // 3125*256 == 800000 exactly
    int src = srcA[e], tgt = tgtA[e];
    float4 s0 = *(const float4*)(s_src + (size_t)src * 8);
    float4 s1 = *(const float4*)(s_src + (size_t)src * 8 + 4);
    float4 t0 = *(const float4*)(s_tgt + (size_t)tgt * 8);
    float4 t1 = *(const float4*)(s_tgt + (size_t)tgt * 8 + 4);
    float sc[8] = {s0.x + t0.x, s0.y + t0.y, s0.z + t0.z, s0.w + t0.w,
                   s1.x + t1.x, s1.y + t1.y, s1.z + t1.z, s1.w + t1.w};
#pragma unroll
    for (int i = 0; i < 8; i++) sc[i] = sc[i] >= 0.f ? sc[i] : ALPHA * sc[i];
    *(float4*)(scores + (size_t)e * 8)     = make_float4(sc[0], sc[1], sc[2], sc[3]);
    *(float4*)(scores + (size_t)e * 8 + 4) = make_float4(sc[4], sc[5], sc[6], sc[7]);

    float m[8];
#pragma unroll
    for (int i = 0; i < 8; i++) m[i] = sc[i];
#pragma unroll
    for (int off = 1; off < 64; off <<= 1) {
#pragma unroll
        for (int i = 0; i < 8; i++) m[i] = fmaxf(m[i], __shfl_xor(m[i], off, 64));
    }
    int lane = t & 63, wave = t >> 6;
    if (lane == 0) {
#pragma unroll
        for (int i = 0; i < 8; i++) red[wave][i] = m[i];
    }
    __syncthreads();
    if (t < 8) {
        float mm = fmaxf(fmaxf(red[0][t], red[1][t]), fmaxf(red[2][t], red[3][t]));
        atomicMaxF(&maxv[t], mm);
    }
}

// ---------------- k3: exp(clip(score-max)) in-place + denom segment-sum
__global__ __launch_bounds__(256) void k3_exp(const int* __restrict__ tgtA,
                                              float* __restrict__ scores,
                                              float* __restrict__ denom,
                                              const float* __restrict__ maxv) {
    int e = blockIdx.x * 256 + threadIdx.x;
    int tgt = tgtA[e];
    float m[8];
#pragma unroll
    for (int i = 0; i < 8; i++) m[i] = maxv[i];
    float4 v0 = *(const float4*)(scores + (size_t)e * 8);
    float4 v1 = *(const float4*)(scores + (size_t)e * 8 + 4);
    float v[8] = {v0.x, v0.y, v0.z, v0.w, v1.x, v1.y, v1.z, v1.w};
    float ex[8];
#pragma unroll
    for (int i = 0; i < 8; i++)
        ex[i] = __expf(fminf(fmaxf(v[i] - m[i], -20.f), 20.f));
    *(float4*)(scores + (size_t)e * 8)     = make_float4(ex[0], ex[1], ex[2], ex[3]);
    *(float4*)(scores + (size_t)e * 8 + 4) = make_float4(ex[4], ex[5], ex[6], ex[7]);
#pragma unroll
    for (int i = 0; i < 8; i++)
        atomicAdd(&denom[(size_t)tgt * 8 + i], ex[i]);
}

// ---------------- k4: out[tgt] += h[src] * attn   (one wave per edge)
__global__ __launch_bounds__(256) void k4_agg(const int* __restrict__ srcA,
                                              const int* __restrict__ tgtA,
                                              const float* __restrict__ expsc,
                                              const float* __restrict__ denom,
                                              const float* __restrict__ h,
                                              float* __restrict__ outb) {
    int t = threadIdx.x;
    int e = blockIdx.x * 4 + (t >> 6);   // 200000*4 == 800000 exactly
    int lane = t & 63;
    int src = srcA[e], tgt = tgtA[e];
    int q = lane >> 4;
    int h0 = q, h1 = q + 4;
    float a0 = expsc[(size_t)e * 8 + h0] / (denom[(size_t)tgt * 8 + h0] + EPSV);
    float a1 = expsc[(size_t)e * 8 + h1] / (denom[(size_t)tgt * 8 + h1] + EPSV);
    float v0 = h[(size_t)src * 128 + lane];
    float v1 = h[(size_t)src * 128 + 64 + lane];
    atomicAdd(&outb[(size_t)tgt * 128 + lane], a0 * v0);
    atomicAdd(&outb[(size_t)tgt * 128 + 64 + lane], a1 * v1);
}

// ---------------- k5: out += bias (in place)
__global__ __launch_bounds__(256) void k5_out(float* __restrict__ outb,
                                              const float* __restrict__ bias) {
    int i = blockIdx.x * 256 + threadIdx.x;  // 25000 blocks * 256 = 6.4M
    outb[i] += bias[i & 127];
}

extern "C" void kernel_launch(void* const* d_in, const int* in_sizes, int n_in,
                              void* d_out, int out_size, void* d_ws, size_t ws_size,
                              hipStream_t stream) {
    const float* x    = (const float*)d_in[0];
    const int*   ei   = (const int*)d_in[1];
    const float* W    = (const float*)d_in[2];
    const float* a    = (const float*)d_in[3];
    const float* bias = (const float*)d_in[4];
    float* outb = (float*)d_out;

    char* ws = (char*)d_ws;
    // layout (bytes):
    float* h      = (float*)(ws);                        // 25,600,000
    float* s_src  = (float*)(ws + 25600000);             //  1,600,000
    float* s_tgt  = (float*)(ws + 27200000);             //  1,600,000
    float* scores = (float*)(ws + 28800000);             // 25,600,000
    float* denom  = (float*)(ws + 54400000);             //  1,600,000
    float* maxv   = (float*)(ws + 56000000);             //         32

    const int* srcA = ei;
    const int* tgtA = ei + N_EDGES;

    hipLaunchKernelGGL(k_init,    dim3(6641),   dim3(256), 0, stream, outb, denom, maxv);
    hipLaunchKernelGGL(k1_gemm,   dim3(12500),  dim3(256), 0, stream, x, W, a, h, s_src, s_tgt);
    hipLaunchKernelGGL(k2_scores, dim3(3125),   dim3(256), 0, stream, srcA, tgtA, s_src, s_tgt, scores, maxv);
    hipLaunchKernelGGL(k3_exp,    dim3(3125),   dim3(256), 0, stream, tgtA, scores, denom, maxv);
    hipLaunchKernelGGL(k4_agg,    dim3(200000), dim3(256), 0, stream, srcA, tgtA, scores, denom, h, outb);
    hipLaunchKernelGGL(k5_out,    dim3(25000),  dim3(256), 0, stream, outb, bias);
}

// Round 3
// 458.329 us; speedup vs baseline: 2.1154x; 2.1154x over previous
//
#include <hip/hip_runtime.h>
#include <stdint.h>

#define N_NODES 50000
#define N_EDGES 800000
#define IN_F 128
#define HEADS 8
#define HEAD_DIM 16
#define ALPHA 0.2f
#define EPSV 1e-6f

__device__ __forceinline__ void atomicMaxF(float* addr, float val) {
    int* ia = (int*)addr;
    int old = *ia;
    while (__int_as_float(old) < val) {
        int assumed = old;
        old = atomicCAS(ia, assumed, __float_as_int(val));
        if (old == assumed) break;
    }
}

// ---------------- init: zero deg, maxv = -inf
__global__ __launch_bounds__(256) void k_init(int* __restrict__ deg,
                                              float* __restrict__ maxv) {
    int i = blockIdx.x * 256 + threadIdx.x;
    if (i < N_NODES) deg[i] = 0;
    if (i < 8) maxv[i] = -INFINITY;
}

// ---------------- k1: h = x @ W  (+ fused s_src/s_tgt projections)
// one wave per node; lane owns cols c0=lane, c1=lane+64 (col = head*16+d)
__global__ __launch_bounds__(256) void k1_gemm(const float* __restrict__ x,
                                               const float* __restrict__ W,
                                               const float* __restrict__ a,
                                               float* __restrict__ h,
                                               float* __restrict__ s_src,
                                               float* __restrict__ s_tgt) {
    __shared__ float a_s[128];
    __shared__ float a_t[128];
    __shared__ float xrow[4][IN_F];
    int t = threadIdx.x;
    {
        int hh = t >> 5, j = t & 31;
        float v = a[t];
        if (j < 16) a_s[hh * 16 + j] = v;
        else        a_t[hh * 16 + (j - 16)] = v;
    }
    int wave = t >> 6, lane = t & 63;
    int n = blockIdx.x * 4 + wave;   // 12500*4 == 50000 exactly
    const float2* xg = (const float2*)(x + (size_t)n * IN_F);
    float2 pk = xg[lane];
    xrow[wave][2 * lane]     = pk.x;
    xrow[wave][2 * lane + 1] = pk.y;
    __syncthreads();

    int d = lane & 15, q = lane >> 4;
    int h0 = q, h1 = q + 4;
    int base0 = h0 * 2048 + d;     // W[h][f][d] = h*2048 + f*16 + d
    int base1 = h1 * 2048 + d;
    float acc0 = 0.f, acc1 = 0.f;
#pragma unroll 8
    for (int f = 0; f < IN_F; f++) {
        float xv = xrow[wave][f];
        acc0 = fmaf(xv, W[base0 + f * 16], acc0);
        acc1 = fmaf(xv, W[base1 + f * 16], acc1);
    }
    int c0 = lane;
    int c1 = lane + 64;
    h[(size_t)n * 128 + c0] = acc0;
    h[(size_t)n * 128 + c1] = acc1;

    float ps = acc0 * a_s[c0], pt = acc0 * a_t[c0];
    float qs = acc1 * a_s[c1], qt = acc1 * a_t[c1];
#pragma unroll
    for (int off = 1; off < 16; off <<= 1) {
        ps += __shfl_xor(ps, off, 64);
        pt += __shfl_xor(pt, off, 64);
        qs += __shfl_xor(qs, off, 64);
        qt += __shfl_xor(qt, off, 64);
    }
    if (d == 0) {
        s_src[n * 8 + h0] = ps;  s_tgt[n * 8 + h0] = pt;
        s_src[n * 8 + h1] = qs;  s_tgt[n * 8 + h1] = qt;
    }
}

// ---------------- hist: deg[tgt]++
__global__ __launch_bounds__(256) void k_hist(const int* __restrict__ tgtA,
                                              int* __restrict__ deg) {
    int e = blockIdx.x * 256 + threadIdx.x;
    atomicAdd(&deg[tgtA[e]], 1);
}

// ---------------- scan: exclusive prefix sum deg -> rowptr (+ cursor copy)
__global__ __launch_bounds__(1024) void k_scan(const int* __restrict__ deg,
                                               int* __restrict__ rowptr,
                                               int* __restrict__ cursor) {
    __shared__ int wsum[16];
    __shared__ int woff[16];
    __shared__ int chunk_tot;
    int t = threadIdx.x;
    int lane = t & 63, w = t >> 6;
    int base = 0;
    for (int c = 0; c < 49; c++) {   // 49*1024 = 50176 >= 50000
        int idx = c * 1024 + t;
        int v = (idx < N_NODES) ? deg[idx] : 0;
        int inc = v;
#pragma unroll
        for (int off = 1; off < 64; off <<= 1) {
            int nn = __shfl_up(inc, off, 64);
            if (lane >= off) inc += nn;
        }
        if (lane == 63) wsum[w] = inc;
        __syncthreads();
        if (t < 16) {
            int s = wsum[t];
            int inc2 = s;
#pragma unroll
            for (int off = 1; off < 16; off <<= 1) {
                int nn = __shfl_up(inc2, off, 64);
                if (t >= off) inc2 += nn;
            }
            woff[t] = inc2 - s;
            if (t == 15) chunk_tot = inc2;
        }
        __syncthreads();
        int excl = base + woff[w] + (inc - v);
        if (idx < N_NODES) { rowptr[idx] = excl; cursor[idx] = excl; }
        base += chunk_tot;
        __syncthreads();
    }
    if (t == 0) rowptr[N_NODES] = base;
}

// ---------------- scatter: src_sorted by tgt + exact per-head global max
__global__ __launch_bounds__(256) void k_scatter(const int* __restrict__ srcA,
                                                 const int* __restrict__ tgtA,
                                                 int* __restrict__ cursor,
                                                 int* __restrict__ src_sorted,
                                                 const float* __restrict__ s_src,
                                                 const float* __restrict__ s_tgt,
                                                 float* __restrict__ maxv) {
    __shared__ float red[4][8];
    int t = threadIdx.x;
    int e = blockIdx.x * 256 + t;    // 3125*256 == 800000
    int src = srcA[e], tgt = tgtA[e];
    int pos = atomicAdd(&cursor[tgt], 1);
    src_sorted[pos] = src;

    float4 s0 = *(const float4*)(s_src + (size_t)src * 8);
    float4 s1 = *(const float4*)(s_src + (size_t)src * 8 + 4);
    float4 t0 = *(const float4*)(s_tgt + (size_t)tgt * 8);
    float4 t1 = *(const float4*)(s_tgt + (size_t)tgt * 8 + 4);
    float sc[8] = {s0.x + t0.x, s0.y + t0.y, s0.z + t0.z, s0.w + t0.w,
                   s1.x + t1.x, s1.y + t1.y, s1.z + t1.z, s1.w + t1.w};
    float m[8];
#pragma unroll
    for (int i = 0; i < 8; i++) {
        float v = sc[i] >= 0.f ? sc[i] : ALPHA * sc[i];
        m[i] = v;
    }
#pragma unroll
    for (int off = 1; off < 64; off <<= 1) {
#pragma unroll
        for (int i = 0; i < 8; i++) m[i] = fmaxf(m[i], __shfl_xor(m[i], off, 64));
    }
    int lane = t & 63, wave = t >> 6;
    if (lane == 0) {
#pragma unroll
        for (int i = 0; i < 8; i++) red[wave][i] = m[i];
    }
    __syncthreads();
    if (t < 8) {
        float mm = fmaxf(fmaxf(red[0][t], red[1][t]), fmaxf(red[2][t], red[3][t]));
        atomicMaxF(&maxv[t], mm);
    }
}

// ---------------- fused: per-node atomic-free softmax + aggregation + bias
// one wave per node; lane owns cols c0=lane (head lane>>4), c1=lane+64 (head 4+(lane>>4))
__global__ __launch_bounds__(256) void k_fused(const int* __restrict__ rowptr,
                                               const int* __restrict__ src_sorted,
                                               const float* __restrict__ s_src,
                                               const float* __restrict__ s_tgt,
                                               const float* __restrict__ maxv,
                                               const float* __restrict__ h,
                                               const float* __restrict__ bias,
                                               float* __restrict__ outb) {
    int t = threadIdx.x;
    int wave = t >> 6, lane = t & 63;
    int n = blockIdx.x * 4 + wave;   // 12500*4 == 50000
    int h0 = lane >> 4, h1 = 4 + (lane >> 4);
    int c0 = lane, c1 = lane + 64;

    float mh0 = maxv[h0], mh1 = maxv[h1];
    float st0 = s_tgt[(size_t)n * 8 + h0];
    float st1 = s_tgt[(size_t)n * 8 + h1];
    int begin = rowptr[n], end = rowptr[n + 1];

    float acc0 = 0.f, acc1 = 0.f, den0 = 0.f, den1 = 0.f;
    int src_next = (begin < end) ? src_sorted[begin] : 0;
    for (int e = begin; e < end; e++) {
        int src = src_next;
        if (e + 1 < end) src_next = src_sorted[e + 1];
        float ss0 = s_src[(size_t)src * 8 + h0];
        float ss1 = s_src[(size_t)src * 8 + h1];
        float v0 = ss0 + st0, v1 = ss1 + st1;
        v0 = v0 >= 0.f ? v0 : ALPHA * v0;
        v1 = v1 >= 0.f ? v1 : ALPHA * v1;
        float ex0 = __expf(fminf(fmaxf(v0 - mh0, -20.f), 20.f));
        float ex1 = __expf(fminf(fmaxf(v1 - mh1, -20.f), 20.f));
        den0 += ex0;
        den1 += ex1;
        acc0 = fmaf(ex0, h[(size_t)src * 128 + c0], acc0);
        acc1 = fmaf(ex1, h[(size_t)src * 128 + c1], acc1);
    }
    outb[(size_t)n * 128 + c0] = acc0 / (den0 + EPSV) + bias[c0];
    outb[(size_t)n * 128 + c1] = acc1 / (den1 + EPSV) + bias[c1];
}

extern "C" void kernel_launch(void* const* d_in, const int* in_sizes, int n_in,
                              void* d_out, int out_size, void* d_ws, size_t ws_size,
                              hipStream_t stream) {
    const float* x    = (const float*)d_in[0];
    const int*   ei   = (const int*)d_in[1];
    const float* W    = (const float*)d_in[2];
    const float* a    = (const float*)d_in[3];
    const float* bias = (const float*)d_in[4];
    float* outb = (float*)d_out;

    char* ws = (char*)d_ws;
    // layout (bytes):
    float* h          = (float*)(ws);                    // 25,600,000
    float* s_src      = (float*)(ws + 25600000);         //  1,600,000
    float* s_tgt      = (float*)(ws + 27200000);         //  1,600,000
    int*   deg        = (int*)  (ws + 28800000);         //    200,064
    int*   rowptr     = (int*)  (ws + 29000064);         //    200,064
    int*   cursor     = (int*)  (ws + 29200128);         //    200,064
    int*   src_sorted = (int*)  (ws + 29400192);         //  3,200,000
    float* maxv       = (float*)(ws + 32600192);         //         32

    const int* srcA = ei;
    const int* tgtA = ei + N_EDGES;

    hipLaunchKernelGGL(k_init,    dim3(196),   dim3(256),  0, stream, deg, maxv);
    hipLaunchKernelGGL(k1_gemm,   dim3(12500), dim3(256),  0, stream, x, W, a, h, s_src, s_tgt);
    hipLaunchKernelGGL(k_hist,    dim3(3125),  dim3(256),  0, stream, tgtA, deg);
    hipLaunchKernelGGL(k_scan,    dim3(1),     dim3(1024), 0, stream, deg, rowptr, cursor);
    hipLaunchKernelGGL(k_scatter, dim3(3125),  dim3(256),  0, stream, srcA, tgtA, cursor, src_sorted, s_src, s_tgt, maxv);
    hipLaunchKernelGGL(k_fused,   dim3(12500), dim3(256),  0, stream, rowptr, src_sorted, s_src, s_tgt, maxv, h, bias, outb);
}